// Round 1
// baseline (98.086 us; speedup 1.0000x reference)
//
#include <hip/hip_runtime.h>

// Problem constants (fixed by the reference)
#define HF 384
#define WF 384
#define PHH 7
#define PWW 7
#define MG 4
#define CC 64
#define LL 512
#define BB 2

__global__ __launch_bounds__(256) void roi_align_kernel(
    const float* __restrict__ img,      // (B, C, HF, WF)
    const float* __restrict__ boxes,    // (B, L, 4) == (B*L, 4)
    float* __restrict__ out,            // (B*L, C, PH, PW)
    int total)
{
    int idx = blockIdx.x * blockDim.x + threadIdx.x;
    if (idx >= total) return;

    const int bin = idx % (PHH * PWW);
    const int c   = (idx / (PHH * PWW)) % CC;
    const int r   = idx / (PHH * PWW * CC);
    const int b   = r / LL;
    const int ph  = bin / PWW;
    const int pw  = bin % PWW;

    // Combined scale s1*s2 == 1.0 exactly for this problem.
    const float* box = boxes + (size_t)r * 4;
    const float x1 = box[0] - 0.5f;
    const float y1 = box[1] - 0.5f;
    const float x2 = box[2] - 0.5f;
    const float y2 = box[3] - 0.5f;

    const float roi_w = x2 - x1;
    const float roi_h = y2 - y1;
    const float bin_w = roi_w * (1.0f / PWW);
    const float bin_h = roi_h * (1.0f / PHH);

    const float ghf = fminf(fmaxf(ceilf(roi_h * (1.0f / PHH)), 1.0f), (float)MG);
    const float gwf = fminf(fmaxf(ceilf(roi_w * (1.0f / PWW)), 1.0f), (float)MG);
    const int igh = (int)ghf;
    const int igw = (int)gwf;
    const float inv_count = 1.0f / (ghf * gwf);

    const float* __restrict__ plane = img + (size_t)(b * CC + c) * (HF * WF);

    // Precompute separable x taps
    int   xi0[MG], xi1[MG];
    float lxw[MG], hxw[MG];
    bool  xv[MG];
    const float bx = x1 + pw * bin_w;
    const float sw = bin_w / gwf;
    #pragma unroll
    for (int ix = 0; ix < MG; ++ix) {
        if (ix < igw) {
            float x = bx + (ix + 0.5f) * sw;
            xv[ix] = (x > -1.0f) && (x < (float)WF);
            float xc = fminf(fmaxf(x, 0.0f), (float)(WF - 1));
            int x0 = (int)floorf(xc);
            xi0[ix] = x0;
            xi1[ix] = (x0 + 1 < WF) ? (x0 + 1) : (WF - 1);
            float lx = xc - (float)x0;
            lxw[ix] = lx;
            hxw[ix] = 1.0f - lx;
        } else {
            xv[ix] = false; xi0[ix] = 0; xi1[ix] = 0; lxw[ix] = 0.f; hxw[ix] = 0.f;
        }
    }

    float acc = 0.0f;
    const float by = y1 + ph * bin_h;
    const float sh = bin_h / ghf;
    for (int iy = 0; iy < igh; ++iy) {
        float y = by + (iy + 0.5f) * sh;
        bool yv = (y > -1.0f) && (y < (float)HF);
        if (!yv) continue;
        float yc = fminf(fmaxf(y, 0.0f), (float)(HF - 1));
        int y0 = (int)floorf(yc);
        int y1i = (y0 + 1 < HF) ? (y0 + 1) : (HF - 1);
        float ly = yc - (float)y0;
        float hy = 1.0f - ly;
        const float* __restrict__ row0 = plane + (size_t)y0 * WF;
        const float* __restrict__ row1 = plane + (size_t)y1i * WF;
        for (int ix = 0; ix < igw; ++ix) {
            if (!xv[ix]) continue;
            float v00 = row0[xi0[ix]];
            float v01 = row0[xi1[ix]];
            float v10 = row1[xi0[ix]];
            float v11 = row1[xi1[ix]];
            float top = hxw[ix] * v00 + lxw[ix] * v01;
            float bot = hxw[ix] * v10 + lxw[ix] * v11;
            acc += hy * top + ly * bot;
        }
    }

    out[idx] = acc * inv_count;
}

extern "C" void kernel_launch(void* const* d_in, const int* in_sizes, int n_in,
                              void* d_out, int out_size, void* d_ws, size_t ws_size,
                              hipStream_t stream) {
    const float* img   = (const float*)d_in[0];
    const float* boxes = (const float*)d_in[1];
    float* out = (float*)d_out;

    const int total = out_size;  // B*L*C*PH*PW = 1024*64*49
    const int block = 256;
    const int grid = (total + block - 1) / block;
    roi_align_kernel<<<grid, block, 0, stream>>>(img, boxes, out, total);
}